// Round 12
// baseline (141.709 us; speedup 1.0000x reference)
//
#include <hip/hip_runtime.h>
#include <stdint.h>

#define FEAT_STRIDE 16
#define PRE_NMS 6000
#define POST_NMS 300
#define NMS_TH 0.7f

static constexpr int B_ = 2, A_ = 9, H_ = 32, W_ = 32, T_ = 16;
static constexpr int LOC = H_ * W_ * T_;   // 16384
static constexpr int N_ = LOC * A_;        // 147456
static constexpr int NBIN = 65536;
static constexpr int NREP = 8;             // histogram replicas (1 per XCD)
static constexpr int CAP = 8192;           // candidate capacity per batch
static constexpr int NW = 94;              // ceil(6000/64) mask words per row
static constexpr int ROWS = 6016;          // NW*64 padded rows

// Exact threshold: fl32(inter/denom) > 0.7f  <=>  inter >= BMID * denom (real),
// BMID = midpoint(0.7f, nextafter(0.7f)); BMID*(double)denom exact (25+24<=53).
static constexpr double BMID = 0.7000000178813934326171875;

// sortedBox row: [x1,y1,z1,x2, y2,z2,vol,score]; mask: [bb][w][row] transposed.
// band: [bb][row][4] = mask words g..g+3 of row (g = row>>6).

__device__ __forceinline__ uint32_t f2u(float f) {
    uint32_t b = __float_as_uint(f);
    return b ^ ((b >> 31) ? 0xFFFFFFFFu : 0x80000000u);
}
__device__ __forceinline__ float u2f(uint32_t u) {
    uint32_t b = (u >> 31) ? (u ^ 0x80000000u) : ~u;
    return __uint_as_float(b);
}
__device__ __forceinline__ unsigned long long rl64(unsigned long long v, int lane) {
    unsigned int lo = (unsigned int)__builtin_amdgcn_readlane((int)(unsigned int)v, lane);
    unsigned int hi = (unsigned int)__builtin_amdgcn_readlane((int)(unsigned int)(v >> 32), lane);
    return ((unsigned long long)hi << 32) | lo;
}

// 1) replicated histogram of score keys' top-16 bits.
__global__ void hist_kernel(const float* __restrict__ scores_map,
                            unsigned int* __restrict__ histR) {
    int gid = blockIdx.x * blockDim.x + threadIdx.x;
    if (gid >= B_ * N_) return;
    int b = gid / N_;
    int r = gid - b * N_;
    int a = r / LOC;
    int loc = r - a * LOC;
    float sc = scores_map[((size_t)(b * 2 * A_ + A_ + a)) * LOC + loc];
    uint32_t u = f2u(sc);
    int rep = blockIdx.x & (NREP - 1);
    atomicAdd(&histR[((size_t)(rep * B_ + b)) * NBIN + (u >> 16)], 1u);
}

// 2a) per (batch, 1024-bin chunk): block-reduce chunk count over all replicas
__global__ void __launch_bounds__(256) partial_kernel(
        const unsigned int* __restrict__ histR,
        unsigned int* __restrict__ partials) {
    int c = blockIdx.x, bb = blockIdx.y, t = threadIdx.x;
    unsigned int s = 0;
#pragma unroll
    for (int r = 0; r < NREP; ++r) {
        const uint4* h4 = reinterpret_cast<const uint4*>(
            histR + ((size_t)(r * B_ + bb)) * NBIN + c * 1024);
        uint4 v = h4[t];
        s += v.x + v.y + v.z + v.w;
    }
    __shared__ unsigned int red[256];
    red[t] = s;
    __syncthreads();
    for (int off = 128; off > 0; off >>= 1) {
        if (t < off) red[t] += red[t + off];
        __syncthreads();
    }
    if (t == 0) partials[bb * 64 + c] = red[0];
}

// 2b) fold replicas -> suffix offsets (bucket starts) + threshold bin detect
__global__ void __launch_bounds__(256) rewrite_kernel(
        const unsigned int* __restrict__ histR,
        unsigned int* __restrict__ hist,
        unsigned int* __restrict__ binbase,
        const unsigned int* __restrict__ partials,
        unsigned int* __restrict__ thr) {
    int c = blockIdx.x, bb = blockIdx.y, t = threadIdx.x;
    __shared__ unsigned int sp[64];
    __shared__ unsigned int ssum[256];
    if (t < 64) sp[t] = partials[bb * 64 + t];
    uint4 v = {0u, 0u, 0u, 0u};
#pragma unroll
    for (int r = 0; r < NREP; ++r) {
        const uint4* h4 = reinterpret_cast<const uint4*>(
            histR + ((size_t)(r * B_ + bb)) * NBIN + c * 1024);
        uint4 w = h4[t];
        v.x += w.x; v.y += w.y; v.z += w.z; v.w += w.w;
    }
    unsigned int* h = hist + (size_t)bb * NBIN + c * 1024;
    unsigned int* bs = binbase + (size_t)bb * NBIN + c * 1024;
    ssum[t] = v.x + v.y + v.z + v.w;
    __syncthreads();
    unsigned int chunkBase = 0;
    for (int q = c + 1; q < 64; ++q) chunkBase += sp[q];
    for (int off = 1; off < 256; off <<= 1) {
        unsigned int val = (t + off < 256) ? ssum[t + off] : 0u;
        __syncthreads();
        ssum[t] += val;
        __syncthreads();
    }
    unsigned int run = chunkBase + ((t < 255) ? ssum[t + 1] : 0u);
    unsigned int cnt[4] = {v.x, v.y, v.z, v.w};
    unsigned int offv[4];
    for (int q = 3; q >= 0; --q) {
        offv[q] = run;
        unsigned int newrun = run + cnt[q];
        if (run < (unsigned)PRE_NMS && newrun >= (unsigned)PRE_NMS) {
            thr[bb * 2 + 0] = (unsigned)(c * 1024 + t * 4 + q);
            thr[bb * 2 + 1] = newrun;
        }
        run = newrun;
    }
    uint4 o4 = {offv[0], offv[1], offv[2], offv[3]};
    reinterpret_cast<uint4*>(h)[t] = o4;
    reinterpret_cast<uint4*>(bs)[t] = o4;
}

// 3) compact: scatter passing keys into their bin's bucket.
__global__ void __launch_bounds__(256) compact_kernel(
        const float* __restrict__ scores_map,
        const unsigned int* __restrict__ thr,
        unsigned long long* __restrict__ cand,
        unsigned int* __restrict__ hist) {
    int tid = threadIdx.x;
    int gid = blockIdx.x * 256 + tid;
    int b = gid / N_;
    int r = gid - b * N_;
    int a = r / LOC;
    int loc = r - a * LOC;
    float sc = scores_map[((size_t)(b * 2 * A_ + A_ + a)) * LOC + loc];
    uint32_t u = f2u(sc);
    uint32_t bin = u >> 16;
    if (bin >= thr[b * 2]) {
        int n = loc * A_ + a;
        unsigned long long key = ((unsigned long long)u << 18)
                               | (unsigned long long)(N_ - 1 - n);
        unsigned int slot = atomicAdd(&hist[b * NBIN + bin], 1u);
        if (slot < (unsigned)CAP)
            cand[(size_t)b * CAP + slot] = key;
    }
}

// 4) bucket rank + decode: rank = binbase[bin] + (# same-bucket keys greater).
__global__ void __launch_bounds__(256) bucket_decode(
        const unsigned long long* __restrict__ cand,
        const unsigned int* __restrict__ hist,
        const unsigned int* __restrict__ binbase,
        const unsigned int* __restrict__ thr,
        const float* __restrict__ bbox_frame,
        const float* __restrict__ im_info,
        const float* __restrict__ anchors,
        float* __restrict__ sortedBox) {
    int gid = blockIdx.x * 256 + threadIdx.x;
    int bb = gid / CAP;
    int i = gid - bb * CAP;
    int count = (int)thr[bb * 2 + 1];
    if (count > CAP) count = CAP;
    if (i >= count) return;
    const unsigned long long* cb = cand + (size_t)bb * CAP;
    unsigned long long me = cb[i];
    int bin = (int)(me >> 34);
    int start = (int)binbase[bb * NBIN + bin];
    int end = (int)hist[bb * NBIN + bin];
    if (end > count) end = count;
    int rank = start;
    for (int q = start; q < end; ++q)
        rank += (cb[q] > me);
    if (rank >= PRE_NMS) return;

    uint32_t u = (uint32_t)(me >> 18);
    int n = N_ - 1 - (int)(me & 0x3FFFFull);
    int a = n % A_;
    int loc = n / A_;
    int k = loc % T_;
    int j = (loc / T_) % W_;
    int ii = loc / (T_ * W_);

    float ax1 = anchors[a * 6 + 0] + (float)(FEAT_STRIDE * j);
    float ay1 = anchors[a * 6 + 1] + (float)(FEAT_STRIDE * ii);
    float az1 = anchors[a * 6 + 2] + (float)k;
    float ax2 = anchors[a * 6 + 3] + (float)(FEAT_STRIDE * j);
    float ay2 = anchors[a * 6 + 4] + (float)(FEAT_STRIDE * ii);
    float az2 = anchors[a * 6 + 5] + (float)k;
    float aw = ax2 - ax1 + 1.0f, ah = ay2 - ay1 + 1.0f, al = az2 - az1 + 1.0f;
    float acx = ax1 + 0.5f * aw, acy = ay1 + 0.5f * ah, acz = az1 + 0.5f * al;

    const float* dp = bbox_frame + ((size_t)(bb * 6 * A_ + a * 6)) * LOC
                    + ii * (W_ * T_) + j * T_ + k;
    float d0 = dp[0 * LOC], d1 = dp[1 * LOC], d2 = dp[2 * LOC];
    float d3 = dp[3 * LOC], d4 = dp[4 * LOC], d5 = dp[5 * LOC];

    float pcx = d0 * aw + acx, pcy = d1 * ah + acy, pcz = d2 * al + acz;
    float pw = expf(d3) * aw, ph = expf(d4) * ah, pl = expf(d5) * al;

    float x1 = pcx - 0.5f * pw, y1 = pcy - 0.5f * ph, z1 = pcz - 0.5f * pl;
    float x2 = pcx + 0.5f * pw, y2 = pcy + 0.5f * ph, z2 = pcz + 0.5f * pl;

    float lx = im_info[1] - 1.0f, ly = im_info[0] - 1.0f, lz = im_info[2] - 1.0f;
    x1 = fminf(fmaxf(x1, 0.0f), lx); y1 = fminf(fmaxf(y1, 0.0f), ly); z1 = fminf(fmaxf(z1, 0.0f), lz);
    x2 = fminf(fmaxf(x2, 0.0f), lx); y2 = fminf(fmaxf(y2, 0.0f), ly); z2 = fminf(fmaxf(z2, 0.0f), lz);

    float vol = (x2 - x1 + 1.0f) * (y2 - y1 + 1.0f) * (z2 - z1 + 1.0f);
    float* p = sortedBox + ((size_t)bb * ROWS + rank) * 8;
    p[0] = x1; p[1] = y1; p[2] = z1; p[3] = x2;
    p[4] = y2; p[5] = z2; p[6] = vol; p[7] = u2f(u);
}

// 5) IoU bitmask (transposed) + 4-word band per row (words g..g+3).
__global__ void mask_build(const float* __restrict__ sortedBox,
                           unsigned long long* __restrict__ mask,
                           unsigned long long* __restrict__ band) {
    int g = blockIdx.x / NW, w = blockIdx.x % NW;
    if (w < g) return;                      // only upper triangle
    int bb = blockIdx.y;
    int lane = threadIdx.x;                 // 64 threads
    __shared__ float4 colA[64];             // x1, y1, z1, x2
    __shared__ float4 colB[64];             // y2, z2, vol, pad
    const float* sb = sortedBox + (size_t)bb * ROWS * 8;
    int col = w * 64 + lane;
    if (col < PRE_NMS) {
        const float4* cp4 = reinterpret_cast<const float4*>(sb + (size_t)col * 8);
        float4 lo = cp4[0], hi = cp4[1];
        colA[lane] = make_float4(lo.x, lo.y, lo.z, lo.w);
        colB[lane] = make_float4(hi.x, hi.y, hi.z, 0.0f);
    } else {
        colA[lane] = make_float4(3e8f, 0.0f, 0.0f, -3e8f);
        colB[lane] = make_float4(0.0f, 0.0f, 1.0f, 0.0f);
    }
    __syncthreads();
    int row = g * 64 + lane;
    if (row >= PRE_NMS) return;
    const float4* rp4 = reinterpret_cast<const float4*>(sb + (size_t)row * 8);
    float4 rlo = rp4[0], rhi = rp4[1];
    float x1 = rlo.x, y1 = rlo.y, z1 = rlo.z;
    float x2 = rlo.w, y2 = rhi.x, z2 = rhi.y, v = rhi.z;
    unsigned long long word = 0;
#pragma unroll 8
    for (int b2 = 0; b2 < 64; ++b2) {
        float4 cA = colA[b2];
        float4 cB = colB[b2];
        float iw = fminf(x2, cA.w) - fmaxf(x1, cA.x) + 1.0f;
        float ih = fminf(y2, cB.x) - fmaxf(y1, cA.y) + 1.0f;
        float il = fminf(z2, cB.y) - fmaxf(z1, cA.z) + 1.0f;
        iw = fmaxf(iw, 0.0f); ih = fmaxf(ih, 0.0f); il = fmaxf(il, 0.0f);
        float inter = iw * ih * il;
        float denom = v + cB.z - inter;
        bool over = ((double)inter >= BMID * (double)denom);  // exact
        int cidx = w * 64 + b2;
        if (cidx > row && over) word |= (1ull << b2);
    }
    mask[((size_t)bb * NW + w) * ROWS + row] = word;
    unsigned long long* bd = band + ((size_t)bb * ROWS + row) * 4;
    if (w == g) {
        bd[0] = word;
        if (g + 1 >= NW) bd[1] = 0ull;
        if (g + 2 >= NW) bd[2] = 0ull;
        if (g + 3 >= NW) bd[3] = 0ull;
    }
    if (w == g + 1) bd[1] = word;
    if (w == g + 2) bd[2] = word;
    if (w == g + 3) bd[3] = word;
}

// 6) suppress v4 — 3-barrier pipeline:
//    keep at chunk k: words k..k+3 covered by wave0 registers (d0..d3 / S1..S3);
//    words >= k+4 via gather: loads ISSUED at iteration k+1 (into the parity pend
//    set), OR'd into remv at k+3 (2 barriers of slack -> latency hidden), visible
//    to scans at iterations >= k+4. Loop unrolled x2 so pend indexing is static.
__global__ void __launch_bounds__(1024) suppress_kernel(
        const unsigned long long* __restrict__ mask,
        const unsigned long long* __restrict__ band,
        const float* __restrict__ sortedBox,
        float* __restrict__ out) {
    int bb = blockIdx.x;
    int tid = threadIdx.x;
    int lane = tid & 63;
    __shared__ unsigned long long remv[NW];
    __shared__ int kr[4][64];
    __shared__ int keptAll[POST_NMS];
    __shared__ int snk[4];
    __shared__ int stot[2];
    for (int i = tid; i < NW; i += 1024) remv[i] = 0ull;
    if (tid == 0) {
        remv[NW - 1] = ~((1ull << (PRE_NMS - (NW - 1) * 64)) - 1ull);
        snk[0] = snk[1] = snk[2] = snk[3] = 0;
        stot[0] = stot[1] = 0;
    }
    __syncthreads();

    const unsigned long long* M  = mask + (size_t)bb * NW * ROWS;
    const unsigned long long* Bd = band + (size_t)bb * ROWS * 4;
    const float* sb = sortedBox + (size_t)bb * ROWS * 8;
    float* ob = out + (size_t)bb * POST_NMS * 7;

    unsigned long long d0 = 0, d1 = 0, d2 = 0, d3 = 0;       // band (chunk c)
    unsigned long long supCur = 0, S1 = 0, S2 = 0, S3 = 0;   // sup words c..c+3
    unsigned long long pendA[8], pendB[8];
    int kept_total = 0;
    int total = 0;
    bool stop = false;
    if (tid < 64) {
        const ulonglong2* bp = reinterpret_cast<const ulonglong2*>(&Bd[(size_t)lane * 4]);
        ulonglong2 v01 = bp[0], v23 = bp[1];
        d0 = v01.x; d1 = v01.y; d2 = v23.x; d3 = v23.y;
    }

#define SUP_STEP(CVAL, PEND)                                                     \
    {                                                                            \
        const int c = (CVAL);                                                    \
        if (tid < 64) {                                                          \
            unsigned long long n0 = 0, n1 = 0, n2 = 0, n3 = 0;                   \
            if (c + 1 < NW) {                                                    \
                const ulonglong2* bp = reinterpret_cast<const ulonglong2*>(      \
                    &Bd[(size_t)((c + 1) * 64 + lane) * 4]);                     \
                ulonglong2 v01 = bp[0], v23 = bp[1];                             \
                n0 = v01.x; n1 = v01.y; n2 = v23.x; n3 = v23.y;                  \
            }                                                                    \
            unsigned long long alive = ~(remv[c] | supCur);                      \
            int nk = 0;                                                          \
            while (alive && kept_total + nk < POST_NMS) {                        \
                int b_ = (int)__builtin_ctzll(alive);                            \
                int bs = __builtin_amdgcn_readfirstlane(b_);                     \
                unsigned long long dr = rl64(d0, bs);                            \
                if (lane == 0) {                                                 \
                    kr[c & 3][nk] = c * 64 + bs;                                 \
                    keptAll[kept_total + nk] = c * 64 + bs;                      \
                }                                                                \
                S1 |= rl64(d1, bs);                                              \
                S2 |= rl64(d2, bs);                                              \
                S3 |= rl64(d3, bs);                                              \
                ++nk;                                                            \
                alive &= ~(dr | (1ull << bs));                                   \
            }                                                                    \
            kept_total += nk;                                                    \
            if (lane == 0) { snk[c & 3] = nk; stot[c & 1] = kept_total; }        \
            supCur = S1; S1 = S2; S2 = S3; S3 = 0;                               \
            d0 = n0; d1 = n1; d2 = n2; d3 = n3;                                  \
        } else {                                                                 \
            int t = tid - 64;                                                    \
            int wi = t >> 3, s = t & 7;                                          \
            if (c >= 3) {                   /* consume keeps[c-3] */             \
                int k = c - 3;                                                   \
                int w = k + 4 + wi;                                              \
                int nk2 = snk[k & 3];                                            \
                if (w < NW && nk2 > 0) {                                         \
                    unsigned long long acc = 0;                                  \
                    _Pragma("unroll")                                            \
                    for (int q = 0; q < 8; ++q) {                                \
                        int i = s + q * 8;                                       \
                        if (i < nk2) acc |= PEND[q];                             \
                    }                                                            \
                    if (acc) atomicOr(&remv[w], acc);                            \
                }                                                                \
            }                                                                    \
            if (c >= 1) {                   /* issue loads for keeps[c-1] */     \
                int k = c - 1;                                                   \
                int w = k + 4 + wi;                                              \
                int nk1 = snk[k & 3];                                            \
                if (w < NW) {                                                    \
                    _Pragma("unroll")                                            \
                    for (int q = 0; q < 8; ++q) {                                \
                        int i = s + q * 8;                                       \
                        if (i < nk1) PEND[q] = M[(size_t)w * ROWS + kr[k & 3][i]]; \
                    }                                                            \
                }                                                                \
            }                                                                    \
        }                                                                        \
        asm volatile("s_waitcnt lgkmcnt(0)" ::: "memory");                       \
        __builtin_amdgcn_s_barrier();                                            \
        asm volatile("" ::: "memory");                                           \
        total = stot[c & 1];                                                     \
        if (total >= POST_NMS) stop = true;                                      \
    }

    for (int cc = 0; cc < NW && !stop; cc += 2) {
        SUP_STEP(cc, pendB);        // even c: consume pendB (issued at c-2, even)
        if (!stop) {
            SUP_STEP(cc + 1, pendA);   // odd c: consume pendA (issued at c-2, odd)
        }
    }
#undef SUP_STEP

    // write outputs: [score, x1,y1,z1,x2,y2,z2] from sb row [x1..z2, vol, score]
    for (int e = tid; e < total * 7; e += 1024) {
        int i = e / 7, j = e - i * 7;
        ob[e] = sb[(size_t)keptAll[i] * 8 + (j == 0 ? 7 : j - 1)];
    }
    for (int idx = total * 7 + tid; idx < POST_NMS * 7; idx += 1024)
        ob[idx] = 0.0f;
}

extern "C" void kernel_launch(void* const* d_in, const int* in_sizes, int n_in,
                              void* d_out, int out_size, void* d_ws, size_t ws_size,
                              hipStream_t stream) {
    const float* scores_map = (const float*)d_in[0];
    const float* bbox_frame = (const float*)d_in[1];
    const float* im_info    = (const float*)d_in[2];
    const float* anchors    = (const float*)d_in[3];
    float* out = (float*)d_out;

    // workspace layout (bytes) — total 10,088,976 (same footprint)
    char* ws = (char*)d_ws;
    unsigned long long* mask  = (unsigned long long*)(ws + 0);          // 9,048,064
    unsigned int* binbase     = (unsigned int*)(ws + 0);                // aliases mask
    unsigned int* histR       = (unsigned int*)(ws + 524288);           // aliases mask: 4,194,304
    float* sortedBox          = (float*)(ws + 9048064);                 // 385,024
    unsigned long long* cand  = (unsigned long long*)(ws + 9433088);    // 131,072
    unsigned int* hist        = (unsigned int*)(ws + 9564160);          // 524,288 canonical
    unsigned long long* band  = (unsigned long long*)(ws + 9564160);    // aliases hist
                                                                        // (hist dead after decode) 385,024
    unsigned int* thr         = (unsigned int*)(ws + 10088448);         // 16
    unsigned int* partials    = (unsigned int*)(ws + 10088464);         // 512

    hipMemsetAsync(histR, 0, (size_t)NREP * B_ * NBIN * 4, stream);

    int total = B_ * N_;
    hist_kernel<<<(total + 255) / 256, 256, 0, stream>>>(scores_map, histR);
    partial_kernel<<<dim3(64, B_), 256, 0, stream>>>(histR, partials);
    rewrite_kernel<<<dim3(64, B_), 256, 0, stream>>>(histR, hist, binbase, partials, thr);
    compact_kernel<<<total / 256, 256, 0, stream>>>(scores_map, thr, cand, hist);
    bucket_decode<<<B_ * CAP / 256, 256, 0, stream>>>(cand, hist, binbase, thr,
                                                      bbox_frame, im_info, anchors,
                                                      sortedBox);
    mask_build<<<dim3(NW * NW, B_), 64, 0, stream>>>(sortedBox, mask, band);
    suppress_kernel<<<B_, 1024, 0, stream>>>(mask, band, sortedBox, out);
}

// Round 13
// 139.680 us; speedup vs baseline: 1.0145x; 1.0145x over previous
//
#include <hip/hip_runtime.h>
#include <stdint.h>

#define FEAT_STRIDE 16
#define PRE_NMS 6000
#define POST_NMS 300
#define NMS_TH 0.7f

static constexpr int B_ = 2, A_ = 9, H_ = 32, W_ = 32, T_ = 16;
static constexpr int LOC = H_ * W_ * T_;   // 16384
static constexpr int N_ = LOC * A_;        // 147456
static constexpr int NBIN = 65536;
static constexpr int NREP = 8;             // histogram replicas (1 per XCD)
static constexpr int CAP = 8192;           // candidate capacity per batch
static constexpr int NW = 94;              // ceil(6000/64) mask words per row
static constexpr int ROWS = 6016;          // NW*64 padded rows

// Exact threshold: fl32(inter/denom) > 0.7f  <=>  inter >= BMID * denom (real),
// BMID = midpoint(0.7f, nextafter(0.7f)); BMID*(double)denom exact (25+24<=53).
static constexpr double BMID = 0.7000000178813934326171875;

// sortedBox row: [x1,y1,z1,x2, y2,z2,vol,score]; mask: [bb][w][row] transposed.
// band: [bb][row][4] = mask words g..g+3 of row (g = row>>6).

__device__ __forceinline__ uint32_t f2u(float f) {
    uint32_t b = __float_as_uint(f);
    return b ^ ((b >> 31) ? 0xFFFFFFFFu : 0x80000000u);
}
__device__ __forceinline__ float u2f(uint32_t u) {
    uint32_t b = (u >> 31) ? (u ^ 0x80000000u) : ~u;
    return __uint_as_float(b);
}
__device__ __forceinline__ unsigned long long rl64(unsigned long long v, int lane) {
    unsigned int lo = (unsigned int)__builtin_amdgcn_readlane((int)(unsigned int)v, lane);
    unsigned int hi = (unsigned int)__builtin_amdgcn_readlane((int)(unsigned int)(v >> 32), lane);
    return ((unsigned long long)hi << 32) | lo;
}

// 1) replicated histogram of score keys' top-16 bits.
__global__ void hist_kernel(const float* __restrict__ scores_map,
                            unsigned int* __restrict__ histR) {
    int gid = blockIdx.x * blockDim.x + threadIdx.x;
    if (gid >= B_ * N_) return;
    int b = gid / N_;
    int r = gid - b * N_;
    int a = r / LOC;
    int loc = r - a * LOC;
    float sc = scores_map[((size_t)(b * 2 * A_ + A_ + a)) * LOC + loc];
    uint32_t u = f2u(sc);
    int rep = blockIdx.x & (NREP - 1);
    atomicAdd(&histR[((size_t)(rep * B_ + b)) * NBIN + (u >> 16)], 1u);
}

// 2a) per (batch, 1024-bin chunk): block-reduce chunk count over all replicas
__global__ void __launch_bounds__(256) partial_kernel(
        const unsigned int* __restrict__ histR,
        unsigned int* __restrict__ partials) {
    int c = blockIdx.x, bb = blockIdx.y, t = threadIdx.x;
    unsigned int s = 0;
#pragma unroll
    for (int r = 0; r < NREP; ++r) {
        const uint4* h4 = reinterpret_cast<const uint4*>(
            histR + ((size_t)(r * B_ + bb)) * NBIN + c * 1024);
        uint4 v = h4[t];
        s += v.x + v.y + v.z + v.w;
    }
    __shared__ unsigned int red[256];
    red[t] = s;
    __syncthreads();
    for (int off = 128; off > 0; off >>= 1) {
        if (t < off) red[t] += red[t + off];
        __syncthreads();
    }
    if (t == 0) partials[bb * 64 + c] = red[0];
}

// 2b) fold replicas -> suffix offsets (bucket starts) + threshold bin detect
__global__ void __launch_bounds__(256) rewrite_kernel(
        const unsigned int* __restrict__ histR,
        unsigned int* __restrict__ hist,
        unsigned int* __restrict__ binbase,
        const unsigned int* __restrict__ partials,
        unsigned int* __restrict__ thr) {
    int c = blockIdx.x, bb = blockIdx.y, t = threadIdx.x;
    __shared__ unsigned int sp[64];
    __shared__ unsigned int ssum[256];
    if (t < 64) sp[t] = partials[bb * 64 + t];
    uint4 v = {0u, 0u, 0u, 0u};
#pragma unroll
    for (int r = 0; r < NREP; ++r) {
        const uint4* h4 = reinterpret_cast<const uint4*>(
            histR + ((size_t)(r * B_ + bb)) * NBIN + c * 1024);
        uint4 w = h4[t];
        v.x += w.x; v.y += w.y; v.z += w.z; v.w += w.w;
    }
    unsigned int* h = hist + (size_t)bb * NBIN + c * 1024;
    unsigned int* bs = binbase + (size_t)bb * NBIN + c * 1024;
    ssum[t] = v.x + v.y + v.z + v.w;
    __syncthreads();
    unsigned int chunkBase = 0;
    for (int q = c + 1; q < 64; ++q) chunkBase += sp[q];
    for (int off = 1; off < 256; off <<= 1) {
        unsigned int val = (t + off < 256) ? ssum[t + off] : 0u;
        __syncthreads();
        ssum[t] += val;
        __syncthreads();
    }
    unsigned int run = chunkBase + ((t < 255) ? ssum[t + 1] : 0u);
    unsigned int cnt[4] = {v.x, v.y, v.z, v.w};
    unsigned int offv[4];
    for (int q = 3; q >= 0; --q) {
        offv[q] = run;
        unsigned int newrun = run + cnt[q];
        if (run < (unsigned)PRE_NMS && newrun >= (unsigned)PRE_NMS) {
            thr[bb * 2 + 0] = (unsigned)(c * 1024 + t * 4 + q);
            thr[bb * 2 + 1] = newrun;
        }
        run = newrun;
    }
    uint4 o4 = {offv[0], offv[1], offv[2], offv[3]};
    reinterpret_cast<uint4*>(h)[t] = o4;
    reinterpret_cast<uint4*>(bs)[t] = o4;
}

// 3) compact: scatter passing keys into their bin's bucket.
__global__ void __launch_bounds__(256) compact_kernel(
        const float* __restrict__ scores_map,
        const unsigned int* __restrict__ thr,
        unsigned long long* __restrict__ cand,
        unsigned int* __restrict__ hist) {
    int tid = threadIdx.x;
    int gid = blockIdx.x * 256 + tid;
    int b = gid / N_;
    int r = gid - b * N_;
    int a = r / LOC;
    int loc = r - a * LOC;
    float sc = scores_map[((size_t)(b * 2 * A_ + A_ + a)) * LOC + loc];
    uint32_t u = f2u(sc);
    uint32_t bin = u >> 16;
    if (bin >= thr[b * 2]) {
        int n = loc * A_ + a;
        unsigned long long key = ((unsigned long long)u << 18)
                               | (unsigned long long)(N_ - 1 - n);
        unsigned int slot = atomicAdd(&hist[b * NBIN + bin], 1u);
        if (slot < (unsigned)CAP)
            cand[(size_t)b * CAP + slot] = key;
    }
}

// 4) bucket rank + decode: rank = binbase[bin] + (# same-bucket keys greater).
__global__ void __launch_bounds__(256) bucket_decode(
        const unsigned long long* __restrict__ cand,
        const unsigned int* __restrict__ hist,
        const unsigned int* __restrict__ binbase,
        const unsigned int* __restrict__ thr,
        const float* __restrict__ bbox_frame,
        const float* __restrict__ im_info,
        const float* __restrict__ anchors,
        float* __restrict__ sortedBox) {
    int gid = blockIdx.x * 256 + threadIdx.x;
    int bb = gid / CAP;
    int i = gid - bb * CAP;
    int count = (int)thr[bb * 2 + 1];
    if (count > CAP) count = CAP;
    if (i >= count) return;
    const unsigned long long* cb = cand + (size_t)bb * CAP;
    unsigned long long me = cb[i];
    int bin = (int)(me >> 34);
    int start = (int)binbase[bb * NBIN + bin];
    int end = (int)hist[bb * NBIN + bin];
    if (end > count) end = count;
    int rank = start;
    for (int q = start; q < end; ++q)
        rank += (cb[q] > me);
    if (rank >= PRE_NMS) return;

    uint32_t u = (uint32_t)(me >> 18);
    int n = N_ - 1 - (int)(me & 0x3FFFFull);
    int a = n % A_;
    int loc = n / A_;
    int k = loc % T_;
    int j = (loc / T_) % W_;
    int ii = loc / (T_ * W_);

    float ax1 = anchors[a * 6 + 0] + (float)(FEAT_STRIDE * j);
    float ay1 = anchors[a * 6 + 1] + (float)(FEAT_STRIDE * ii);
    float az1 = anchors[a * 6 + 2] + (float)k;
    float ax2 = anchors[a * 6 + 3] + (float)(FEAT_STRIDE * j);
    float ay2 = anchors[a * 6 + 4] + (float)(FEAT_STRIDE * ii);
    float az2 = anchors[a * 6 + 5] + (float)k;
    float aw = ax2 - ax1 + 1.0f, ah = ay2 - ay1 + 1.0f, al = az2 - az1 + 1.0f;
    float acx = ax1 + 0.5f * aw, acy = ay1 + 0.5f * ah, acz = az1 + 0.5f * al;

    const float* dp = bbox_frame + ((size_t)(bb * 6 * A_ + a * 6)) * LOC
                    + ii * (W_ * T_) + j * T_ + k;
    float d0 = dp[0 * LOC], d1 = dp[1 * LOC], d2 = dp[2 * LOC];
    float d3 = dp[3 * LOC], d4 = dp[4 * LOC], d5 = dp[5 * LOC];

    float pcx = d0 * aw + acx, pcy = d1 * ah + acy, pcz = d2 * al + acz;
    float pw = expf(d3) * aw, ph = expf(d4) * ah, pl = expf(d5) * al;

    float x1 = pcx - 0.5f * pw, y1 = pcy - 0.5f * ph, z1 = pcz - 0.5f * pl;
    float x2 = pcx + 0.5f * pw, y2 = pcy + 0.5f * ph, z2 = pcz + 0.5f * pl;

    float lx = im_info[1] - 1.0f, ly = im_info[0] - 1.0f, lz = im_info[2] - 1.0f;
    x1 = fminf(fmaxf(x1, 0.0f), lx); y1 = fminf(fmaxf(y1, 0.0f), ly); z1 = fminf(fmaxf(z1, 0.0f), lz);
    x2 = fminf(fmaxf(x2, 0.0f), lx); y2 = fminf(fmaxf(y2, 0.0f), ly); z2 = fminf(fmaxf(z2, 0.0f), lz);

    float vol = (x2 - x1 + 1.0f) * (y2 - y1 + 1.0f) * (z2 - z1 + 1.0f);
    float* p = sortedBox + ((size_t)bb * ROWS + rank) * 8;
    p[0] = x1; p[1] = y1; p[2] = z1; p[3] = x2;
    p[4] = y2; p[5] = z2; p[6] = vol; p[7] = u2f(u);
}

// 5) IoU bitmask (transposed) + 4-word band per row (words g..g+3).
__global__ void mask_build(const float* __restrict__ sortedBox,
                           unsigned long long* __restrict__ mask,
                           unsigned long long* __restrict__ band) {
    int g = blockIdx.x / NW, w = blockIdx.x % NW;
    if (w < g) return;                      // only upper triangle
    int bb = blockIdx.y;
    int lane = threadIdx.x;                 // 64 threads
    __shared__ float4 colA[64];             // x1, y1, z1, x2
    __shared__ float4 colB[64];             // y2, z2, vol, pad
    const float* sb = sortedBox + (size_t)bb * ROWS * 8;
    int col = w * 64 + lane;
    if (col < PRE_NMS) {
        const float4* cp4 = reinterpret_cast<const float4*>(sb + (size_t)col * 8);
        float4 lo = cp4[0], hi = cp4[1];
        colA[lane] = make_float4(lo.x, lo.y, lo.z, lo.w);
        colB[lane] = make_float4(hi.x, hi.y, hi.z, 0.0f);
    } else {
        colA[lane] = make_float4(3e8f, 0.0f, 0.0f, -3e8f);
        colB[lane] = make_float4(0.0f, 0.0f, 1.0f, 0.0f);
    }
    __syncthreads();
    int row = g * 64 + lane;
    if (row >= PRE_NMS) return;
    const float4* rp4 = reinterpret_cast<const float4*>(sb + (size_t)row * 8);
    float4 rlo = rp4[0], rhi = rp4[1];
    float x1 = rlo.x, y1 = rlo.y, z1 = rlo.z;
    float x2 = rlo.w, y2 = rhi.x, z2 = rhi.y, v = rhi.z;
    unsigned long long word = 0;
#pragma unroll 8
    for (int b2 = 0; b2 < 64; ++b2) {
        float4 cA = colA[b2];
        float4 cB = colB[b2];
        float iw = fminf(x2, cA.w) - fmaxf(x1, cA.x) + 1.0f;
        float ih = fminf(y2, cB.x) - fmaxf(y1, cA.y) + 1.0f;
        float il = fminf(z2, cB.y) - fmaxf(z1, cA.z) + 1.0f;
        iw = fmaxf(iw, 0.0f); ih = fmaxf(ih, 0.0f); il = fmaxf(il, 0.0f);
        float inter = iw * ih * il;
        float denom = v + cB.z - inter;
        bool over = ((double)inter >= BMID * (double)denom);  // exact
        int cidx = w * 64 + b2;
        if (cidx > row && over) word |= (1ull << b2);
    }
    mask[((size_t)bb * NW + w) * ROWS + row] = word;
    unsigned long long* bd = band + ((size_t)bb * ROWS + row) * 4;
    if (w == g) {
        bd[0] = word;
        if (g + 1 >= NW) bd[1] = 0ull;
        if (g + 2 >= NW) bd[2] = 0ull;
        if (g + 3 >= NW) bd[3] = 0ull;
    }
    if (w == g + 1) bd[1] = word;
    if (w == g + 2) bd[2] = word;
    if (w == g + 3) bd[3] = word;
}

// 6) suppress v5 — producer/consumer wave specialization, NO barriers in loop.
//    wave0: serial scan; band regs (2-deep parity prefetch) cover words k..k+3;
//    publishes keeps via LDS + release 'scanned'. waves 1..3: free-running
//    gatherers (set k -> wave k%3): OR mask rows into remv words >= k+4, bump
//    'applied'. wave0 gates scan of chunk c on applied[*] > c-4.
__global__ void __launch_bounds__(256) suppress_kernel(
        const unsigned long long* __restrict__ mask,
        const unsigned long long* __restrict__ band,
        const float* __restrict__ sortedBox,
        float* __restrict__ out) {
    int bb = blockIdx.x;
    int tid = threadIdx.x;
    int lane = tid & 63, wv = tid >> 6;
    __shared__ unsigned long long remv[NW];
    __shared__ int kr[8][64];
    __shared__ int keptAll[POST_NMS];
    __shared__ int snk[8];
    __shared__ int scanned;
    __shared__ int applied[3];
    __shared__ int stopf;
    __shared__ int stotal;
    for (int i = tid; i < NW; i += 256) remv[i] = 0ull;
    if (tid == 0) {
        remv[NW - 1] = ~((1ull << (PRE_NMS - (NW - 1) * 64)) - 1ull);
        scanned = 0; stopf = 0; stotal = 0;
        applied[0] = 0; applied[1] = 1; applied[2] = 2;
        for (int q = 0; q < 8; ++q) snk[q] = 0;
    }
    __syncthreads();

    const unsigned long long* M  = mask + (size_t)bb * NW * ROWS;
    const unsigned long long* Bd = band + (size_t)bb * ROWS * 4;
    const float* sb = sortedBox + (size_t)bb * ROWS * 8;
    float* ob = out + (size_t)bb * POST_NMS * 7;

    if (wv == 0) {
        // ---- scan wave ----
        unsigned long long a0, a1, a2, a3, b0, b1, b2, b3;   // band parity sets
        {
            const ulonglong2* bp = reinterpret_cast<const ulonglong2*>(&Bd[(size_t)lane * 4]);
            ulonglong2 v01 = bp[0], v23 = bp[1];
            a0 = v01.x; a1 = v01.y; a2 = v23.x; a3 = v23.y;
        }
        {
            const ulonglong2* bp = reinterpret_cast<const ulonglong2*>(&Bd[(size_t)(64 + lane) * 4]);
            ulonglong2 v01 = bp[0], v23 = bp[1];
            b0 = v01.x; b1 = v01.y; b2 = v23.x; b3 = v23.y;
        }
        unsigned long long supCur = 0, S1 = 0, S2 = 0, S3 = 0;
        int kept_total = 0;
        bool stop = false;

#define SUP_STEP(CVAL, D0, D1, D2, D3)                                          \
        {                                                                       \
            const int c = (CVAL);                                               \
            if (c >= 4) {                                                       \
                while (true) {                                                  \
                    int x0 = __hip_atomic_load(&applied[0], __ATOMIC_RELAXED,   \
                                               __HIP_MEMORY_SCOPE_WORKGROUP);   \
                    int x1 = __hip_atomic_load(&applied[1], __ATOMIC_RELAXED,   \
                                               __HIP_MEMORY_SCOPE_WORKGROUP);   \
                    int x2 = __hip_atomic_load(&applied[2], __ATOMIC_RELAXED,   \
                                               __HIP_MEMORY_SCOPE_WORKGROUP);   \
                    if (x0 > c - 4 && x1 > c - 4 && x2 > c - 4) break;          \
                    __builtin_amdgcn_s_sleep(1);                                \
                }                                                               \
                __threadfence_block();                                          \
            }                                                                   \
            unsigned long long alive = ~(remv[c] | supCur);                     \
            int nk = 0;                                                         \
            while (alive && kept_total + nk < POST_NMS) {                       \
                int b_ = (int)__builtin_ctzll(alive);                           \
                int bs = __builtin_amdgcn_readfirstlane(b_);                    \
                unsigned long long dr = rl64(D0, bs);                           \
                if (lane == 0) {                                                \
                    kr[c & 7][nk] = c * 64 + bs;                                \
                    keptAll[kept_total + nk] = c * 64 + bs;                     \
                }                                                               \
                S1 |= rl64(D1, bs);                                             \
                S2 |= rl64(D2, bs);                                             \
                S3 |= rl64(D3, bs);                                             \
                ++nk;                                                           \
                alive &= ~(dr | (1ull << bs));                                  \
            }                                                                   \
            kept_total += nk;                                                   \
            if (lane == 0) {                                                    \
                snk[c & 7] = nk;                                                \
                __hip_atomic_store(&scanned, c + 1, __ATOMIC_RELEASE,           \
                                   __HIP_MEMORY_SCOPE_WORKGROUP);               \
            }                                                                   \
            supCur = S1; S1 = S2; S2 = S3; S3 = 0;                              \
            if (kept_total >= POST_NMS) {                                       \
                stop = true;                                                    \
            } else if (c + 2 < NW) {                                            \
                const ulonglong2* bp = reinterpret_cast<const ulonglong2*>(     \
                    &Bd[(size_t)((c + 2) * 64 + lane) * 4]);                    \
                ulonglong2 v01 = bp[0], v23 = bp[1];                            \
                D0 = v01.x; D1 = v01.y; D2 = v23.x; D3 = v23.y;                 \
            }                                                                   \
        }

        for (int cc = 0; cc < NW && !stop; cc += 2) {
            SUP_STEP(cc, a0, a1, a2, a3);
            if (!stop) {
                SUP_STEP(cc + 1, b0, b1, b2, b3);
            }
        }
#undef SUP_STEP
        if (lane == 0) {
            stotal = kept_total;
            __hip_atomic_store(&stopf, 1, __ATOMIC_RELEASE,
                               __HIP_MEMORY_SCOPE_WORKGROUP);
        }
    } else {
        // ---- gather waves (1..3): free-running, no barriers ----
        int gw = wv - 1;
        for (int k = gw; k < NW; k += 3) {
            bool bail = false;
            while (true) {
                int s = __hip_atomic_load(&scanned, __ATOMIC_ACQUIRE,
                                          __HIP_MEMORY_SCOPE_WORKGROUP);
                if (s > k) break;
                if (__hip_atomic_load(&stopf, __ATOMIC_RELAXED,
                                      __HIP_MEMORY_SCOPE_WORKGROUP)) { bail = true; break; }
                __builtin_amdgcn_s_sleep(1);
            }
            if (bail) break;
            int nk = snk[k & 7];
            int W = NW - (k + 4);
            if (nk > 0 && W > 0) {
                int w0 = k + 4 + lane;
                int w1 = w0 + 64;
                bool g0 = lane < W, g1 = lane + 64 < W;
                unsigned long long acc0 = 0, acc1 = 0;
                for (int ib = 0; ib < nk; ib += 4) {
                    int r0 = kr[k & 7][ib];
                    int r1 = (ib + 1 < nk) ? kr[k & 7][ib + 1] : -1;
                    int r2 = (ib + 2 < nk) ? kr[k & 7][ib + 2] : -1;
                    int r3 = (ib + 3 < nk) ? kr[k & 7][ib + 3] : -1;
                    unsigned long long pa0 = 0, pa1 = 0, pb0 = 0, pb1 = 0;
                    unsigned long long pc0 = 0, pc1 = 0, pd0 = 0, pd1 = 0;
                    if (g0) pa0 = M[(size_t)w0 * ROWS + r0];
                    if (g1) pa1 = M[(size_t)w1 * ROWS + r0];
                    if (r1 >= 0) {
                        if (g0) pb0 = M[(size_t)w0 * ROWS + r1];
                        if (g1) pb1 = M[(size_t)w1 * ROWS + r1];
                    }
                    if (r2 >= 0) {
                        if (g0) pc0 = M[(size_t)w0 * ROWS + r2];
                        if (g1) pc1 = M[(size_t)w1 * ROWS + r2];
                    }
                    if (r3 >= 0) {
                        if (g0) pd0 = M[(size_t)w0 * ROWS + r3];
                        if (g1) pd1 = M[(size_t)w1 * ROWS + r3];
                    }
                    acc0 |= pa0 | pb0 | pc0 | pd0;
                    acc1 |= pa1 | pb1 | pc1 | pd1;
                }
                if (g0 && acc0) atomicOr(&remv[w0], acc0);
                if (g1 && acc1) atomicOr(&remv[w1], acc1);
            }
            __threadfence_block();
            __hip_atomic_store(&applied[gw], k + 3, __ATOMIC_RELEASE,
                               __HIP_MEMORY_SCOPE_WORKGROUP);
        }
    }
    __syncthreads();

    int total = stotal;
    for (int e = tid; e < total * 7; e += 256) {
        int i = e / 7, j = e - i * 7;
        ob[e] = sb[(size_t)keptAll[i] * 8 + (j == 0 ? 7 : j - 1)];
    }
    for (int idx = total * 7 + tid; idx < POST_NMS * 7; idx += 256)
        ob[idx] = 0.0f;
}

extern "C" void kernel_launch(void* const* d_in, const int* in_sizes, int n_in,
                              void* d_out, int out_size, void* d_ws, size_t ws_size,
                              hipStream_t stream) {
    const float* scores_map = (const float*)d_in[0];
    const float* bbox_frame = (const float*)d_in[1];
    const float* im_info    = (const float*)d_in[2];
    const float* anchors    = (const float*)d_in[3];
    float* out = (float*)d_out;

    // workspace layout (bytes) — total 10,088,976 (same footprint)
    char* ws = (char*)d_ws;
    unsigned long long* mask  = (unsigned long long*)(ws + 0);          // 9,048,064
    unsigned int* binbase     = (unsigned int*)(ws + 0);                // aliases mask
    unsigned int* histR       = (unsigned int*)(ws + 524288);           // aliases mask: 4,194,304
    float* sortedBox          = (float*)(ws + 9048064);                 // 385,024
    unsigned long long* cand  = (unsigned long long*)(ws + 9433088);    // 131,072
    unsigned int* hist        = (unsigned int*)(ws + 9564160);          // 524,288 canonical
    unsigned long long* band  = (unsigned long long*)(ws + 9564160);    // aliases hist
                                                                        // (hist dead after decode) 385,024
    unsigned int* thr         = (unsigned int*)(ws + 10088448);         // 16
    unsigned int* partials    = (unsigned int*)(ws + 10088464);         // 512

    hipMemsetAsync(histR, 0, (size_t)NREP * B_ * NBIN * 4, stream);

    int total = B_ * N_;
    hist_kernel<<<(total + 255) / 256, 256, 0, stream>>>(scores_map, histR);
    partial_kernel<<<dim3(64, B_), 256, 0, stream>>>(histR, partials);
    rewrite_kernel<<<dim3(64, B_), 256, 0, stream>>>(histR, hist, binbase, partials, thr);
    compact_kernel<<<total / 256, 256, 0, stream>>>(scores_map, thr, cand, hist);
    bucket_decode<<<B_ * CAP / 256, 256, 0, stream>>>(cand, hist, binbase, thr,
                                                      bbox_frame, im_info, anchors,
                                                      sortedBox);
    mask_build<<<dim3(NW * NW, B_), 64, 0, stream>>>(sortedBox, mask, band);
    suppress_kernel<<<B_, 256, 0, stream>>>(mask, band, sortedBox, out);
}

// Round 14
// 136.366 us; speedup vs baseline: 1.0392x; 1.0243x over previous
//
#include <hip/hip_runtime.h>
#include <stdint.h>

#define FEAT_STRIDE 16
#define PRE_NMS 6000
#define POST_NMS 300
#define NMS_TH 0.7f

static constexpr int B_ = 2, A_ = 9, H_ = 32, W_ = 32, T_ = 16;
static constexpr int LOC = H_ * W_ * T_;   // 16384
static constexpr int N_ = LOC * A_;        // 147456
static constexpr int NBIN = 65536;
static constexpr int NREP = 8;             // histogram replicas (1 per XCD)
static constexpr int CAP = 8192;           // candidate capacity per batch
static constexpr int NW = 94;              // ceil(6000/64) mask words per row
static constexpr int ROWS = 6016;          // NW*64 padded rows

// Exact threshold: fl32(inter/denom) > 0.7f  <=>  inter >= BMID * denom (real),
// BMID = midpoint(0.7f, nextafter(0.7f)); BMID*(double)denom exact (25+24<=53).
static constexpr double BMID = 0.7000000178813934326171875;

// sortedBox row: [x1,y1,z1,x2, y2,z2,vol,score]; mask: [bb][w][row] transposed.
// band: [bb][row][4] = mask words g..g+3 of row (g = row>>6); word 3 unused here.

__device__ __forceinline__ uint32_t f2u(float f) {
    uint32_t b = __float_as_uint(f);
    return b ^ ((b >> 31) ? 0xFFFFFFFFu : 0x80000000u);
}
__device__ __forceinline__ float u2f(uint32_t u) {
    uint32_t b = (u >> 31) ? (u ^ 0x80000000u) : ~u;
    return __uint_as_float(b);
}
__device__ __forceinline__ unsigned long long rl64(unsigned long long v, int lane) {
    unsigned int lo = (unsigned int)__builtin_amdgcn_readlane((int)(unsigned int)v, lane);
    unsigned int hi = (unsigned int)__builtin_amdgcn_readlane((int)(unsigned int)(v >> 32), lane);
    return ((unsigned long long)hi << 32) | lo;
}

// 1) replicated histogram of score keys' top-16 bits.
__global__ void hist_kernel(const float* __restrict__ scores_map,
                            unsigned int* __restrict__ histR) {
    int gid = blockIdx.x * blockDim.x + threadIdx.x;
    if (gid >= B_ * N_) return;
    int b = gid / N_;
    int r = gid - b * N_;
    int a = r / LOC;
    int loc = r - a * LOC;
    float sc = scores_map[((size_t)(b * 2 * A_ + A_ + a)) * LOC + loc];
    uint32_t u = f2u(sc);
    int rep = blockIdx.x & (NREP - 1);
    atomicAdd(&histR[((size_t)(rep * B_ + b)) * NBIN + (u >> 16)], 1u);
}

// 2a) per (batch, 1024-bin chunk): block-reduce chunk count over all replicas
__global__ void __launch_bounds__(256) partial_kernel(
        const unsigned int* __restrict__ histR,
        unsigned int* __restrict__ partials) {
    int c = blockIdx.x, bb = blockIdx.y, t = threadIdx.x;
    unsigned int s = 0;
#pragma unroll
    for (int r = 0; r < NREP; ++r) {
        const uint4* h4 = reinterpret_cast<const uint4*>(
            histR + ((size_t)(r * B_ + bb)) * NBIN + c * 1024);
        uint4 v = h4[t];
        s += v.x + v.y + v.z + v.w;
    }
    __shared__ unsigned int red[256];
    red[t] = s;
    __syncthreads();
    for (int off = 128; off > 0; off >>= 1) {
        if (t < off) red[t] += red[t + off];
        __syncthreads();
    }
    if (t == 0) partials[bb * 64 + c] = red[0];
}

// 2b) fold replicas -> suffix offsets (bucket starts) + threshold bin detect
__global__ void __launch_bounds__(256) rewrite_kernel(
        const unsigned int* __restrict__ histR,
        unsigned int* __restrict__ hist,
        unsigned int* __restrict__ binbase,
        const unsigned int* __restrict__ partials,
        unsigned int* __restrict__ thr) {
    int c = blockIdx.x, bb = blockIdx.y, t = threadIdx.x;
    __shared__ unsigned int sp[64];
    __shared__ unsigned int ssum[256];
    if (t < 64) sp[t] = partials[bb * 64 + t];
    uint4 v = {0u, 0u, 0u, 0u};
#pragma unroll
    for (int r = 0; r < NREP; ++r) {
        const uint4* h4 = reinterpret_cast<const uint4*>(
            histR + ((size_t)(r * B_ + bb)) * NBIN + c * 1024);
        uint4 w = h4[t];
        v.x += w.x; v.y += w.y; v.z += w.z; v.w += w.w;
    }
    unsigned int* h = hist + (size_t)bb * NBIN + c * 1024;
    unsigned int* bs = binbase + (size_t)bb * NBIN + c * 1024;
    ssum[t] = v.x + v.y + v.z + v.w;
    __syncthreads();
    unsigned int chunkBase = 0;
    for (int q = c + 1; q < 64; ++q) chunkBase += sp[q];
    for (int off = 1; off < 256; off <<= 1) {
        unsigned int val = (t + off < 256) ? ssum[t + off] : 0u;
        __syncthreads();
        ssum[t] += val;
        __syncthreads();
    }
    unsigned int run = chunkBase + ((t < 255) ? ssum[t + 1] : 0u);
    unsigned int cnt[4] = {v.x, v.y, v.z, v.w};
    unsigned int offv[4];
    for (int q = 3; q >= 0; --q) {
        offv[q] = run;
        unsigned int newrun = run + cnt[q];
        if (run < (unsigned)PRE_NMS && newrun >= (unsigned)PRE_NMS) {
            thr[bb * 2 + 0] = (unsigned)(c * 1024 + t * 4 + q);
            thr[bb * 2 + 1] = newrun;
        }
        run = newrun;
    }
    uint4 o4 = {offv[0], offv[1], offv[2], offv[3]};
    reinterpret_cast<uint4*>(h)[t] = o4;
    reinterpret_cast<uint4*>(bs)[t] = o4;
}

// 3) compact: scatter passing keys into their bin's bucket.
__global__ void __launch_bounds__(256) compact_kernel(
        const float* __restrict__ scores_map,
        const unsigned int* __restrict__ thr,
        unsigned long long* __restrict__ cand,
        unsigned int* __restrict__ hist) {
    int tid = threadIdx.x;
    int gid = blockIdx.x * 256 + tid;
    int b = gid / N_;
    int r = gid - b * N_;
    int a = r / LOC;
    int loc = r - a * LOC;
    float sc = scores_map[((size_t)(b * 2 * A_ + A_ + a)) * LOC + loc];
    uint32_t u = f2u(sc);
    uint32_t bin = u >> 16;
    if (bin >= thr[b * 2]) {
        int n = loc * A_ + a;
        unsigned long long key = ((unsigned long long)u << 18)
                               | (unsigned long long)(N_ - 1 - n);
        unsigned int slot = atomicAdd(&hist[b * NBIN + bin], 1u);
        if (slot < (unsigned)CAP)
            cand[(size_t)b * CAP + slot] = key;
    }
}

// 4) bucket rank + decode: rank = binbase[bin] + (# same-bucket keys greater).
__global__ void __launch_bounds__(256) bucket_decode(
        const unsigned long long* __restrict__ cand,
        const unsigned int* __restrict__ hist,
        const unsigned int* __restrict__ binbase,
        const unsigned int* __restrict__ thr,
        const float* __restrict__ bbox_frame,
        const float* __restrict__ im_info,
        const float* __restrict__ anchors,
        float* __restrict__ sortedBox) {
    int gid = blockIdx.x * 256 + threadIdx.x;
    int bb = gid / CAP;
    int i = gid - bb * CAP;
    int count = (int)thr[bb * 2 + 1];
    if (count > CAP) count = CAP;
    if (i >= count) return;
    const unsigned long long* cb = cand + (size_t)bb * CAP;
    unsigned long long me = cb[i];
    int bin = (int)(me >> 34);
    int start = (int)binbase[bb * NBIN + bin];
    int end = (int)hist[bb * NBIN + bin];
    if (end > count) end = count;
    int rank = start;
    for (int q = start; q < end; ++q)
        rank += (cb[q] > me);
    if (rank >= PRE_NMS) return;

    uint32_t u = (uint32_t)(me >> 18);
    int n = N_ - 1 - (int)(me & 0x3FFFFull);
    int a = n % A_;
    int loc = n / A_;
    int k = loc % T_;
    int j = (loc / T_) % W_;
    int ii = loc / (T_ * W_);

    float ax1 = anchors[a * 6 + 0] + (float)(FEAT_STRIDE * j);
    float ay1 = anchors[a * 6 + 1] + (float)(FEAT_STRIDE * ii);
    float az1 = anchors[a * 6 + 2] + (float)k;
    float ax2 = anchors[a * 6 + 3] + (float)(FEAT_STRIDE * j);
    float ay2 = anchors[a * 6 + 4] + (float)(FEAT_STRIDE * ii);
    float az2 = anchors[a * 6 + 5] + (float)k;
    float aw = ax2 - ax1 + 1.0f, ah = ay2 - ay1 + 1.0f, al = az2 - az1 + 1.0f;
    float acx = ax1 + 0.5f * aw, acy = ay1 + 0.5f * ah, acz = az1 + 0.5f * al;

    const float* dp = bbox_frame + ((size_t)(bb * 6 * A_ + a * 6)) * LOC
                    + ii * (W_ * T_) + j * T_ + k;
    float d0 = dp[0 * LOC], d1 = dp[1 * LOC], d2 = dp[2 * LOC];
    float d3 = dp[3 * LOC], d4 = dp[4 * LOC], d5 = dp[5 * LOC];

    float pcx = d0 * aw + acx, pcy = d1 * ah + acy, pcz = d2 * al + acz;
    float pw = expf(d3) * aw, ph = expf(d4) * ah, pl = expf(d5) * al;

    float x1 = pcx - 0.5f * pw, y1 = pcy - 0.5f * ph, z1 = pcz - 0.5f * pl;
    float x2 = pcx + 0.5f * pw, y2 = pcy + 0.5f * ph, z2 = pcz + 0.5f * pl;

    float lx = im_info[1] - 1.0f, ly = im_info[0] - 1.0f, lz = im_info[2] - 1.0f;
    x1 = fminf(fmaxf(x1, 0.0f), lx); y1 = fminf(fmaxf(y1, 0.0f), ly); z1 = fminf(fmaxf(z1, 0.0f), lz);
    x2 = fminf(fmaxf(x2, 0.0f), lx); y2 = fminf(fmaxf(y2, 0.0f), ly); z2 = fminf(fmaxf(z2, 0.0f), lz);

    float vol = (x2 - x1 + 1.0f) * (y2 - y1 + 1.0f) * (z2 - z1 + 1.0f);
    float* p = sortedBox + ((size_t)bb * ROWS + rank) * 8;
    p[0] = x1; p[1] = y1; p[2] = z1; p[3] = x2;
    p[4] = y2; p[5] = z2; p[6] = vol; p[7] = u2f(u);
}

// 5) IoU bitmask (transposed) + 4-word band per row (words g..g+3).
__global__ void mask_build(const float* __restrict__ sortedBox,
                           unsigned long long* __restrict__ mask,
                           unsigned long long* __restrict__ band) {
    int g = blockIdx.x / NW, w = blockIdx.x % NW;
    if (w < g) return;                      // only upper triangle
    int bb = blockIdx.y;
    int lane = threadIdx.x;                 // 64 threads
    __shared__ float4 colA[64];             // x1, y1, z1, x2
    __shared__ float4 colB[64];             // y2, z2, vol, pad
    const float* sb = sortedBox + (size_t)bb * ROWS * 8;
    int col = w * 64 + lane;
    if (col < PRE_NMS) {
        const float4* cp4 = reinterpret_cast<const float4*>(sb + (size_t)col * 8);
        float4 lo = cp4[0], hi = cp4[1];
        colA[lane] = make_float4(lo.x, lo.y, lo.z, lo.w);
        colB[lane] = make_float4(hi.x, hi.y, hi.z, 0.0f);
    } else {
        colA[lane] = make_float4(3e8f, 0.0f, 0.0f, -3e8f);
        colB[lane] = make_float4(0.0f, 0.0f, 1.0f, 0.0f);
    }
    __syncthreads();
    int row = g * 64 + lane;
    if (row >= PRE_NMS) return;
    const float4* rp4 = reinterpret_cast<const float4*>(sb + (size_t)row * 8);
    float4 rlo = rp4[0], rhi = rp4[1];
    float x1 = rlo.x, y1 = rlo.y, z1 = rlo.z;
    float x2 = rlo.w, y2 = rhi.x, z2 = rhi.y, v = rhi.z;
    unsigned long long word = 0;
#pragma unroll 8
    for (int b2 = 0; b2 < 64; ++b2) {
        float4 cA = colA[b2];
        float4 cB = colB[b2];
        float iw = fminf(x2, cA.w) - fmaxf(x1, cA.x) + 1.0f;
        float ih = fminf(y2, cB.x) - fmaxf(y1, cA.y) + 1.0f;
        float il = fminf(z2, cB.y) - fmaxf(z1, cA.z) + 1.0f;
        iw = fmaxf(iw, 0.0f); ih = fmaxf(ih, 0.0f); il = fmaxf(il, 0.0f);
        float inter = iw * ih * il;
        float denom = v + cB.z - inter;
        bool over = ((double)inter >= BMID * (double)denom);  // exact
        int cidx = w * 64 + b2;
        if (cidx > row && over) word |= (1ull << b2);
    }
    mask[((size_t)bb * NW + w) * ROWS + row] = word;
    unsigned long long* bd = band + ((size_t)bb * ROWS + row) * 4;
    if (w == g) {
        bd[0] = word;
        if (g + 1 >= NW) bd[1] = 0ull;
        if (g + 2 >= NW) bd[2] = 0ull;
        if (g + 3 >= NW) bd[3] = 0ull;
    }
    if (w == g + 1) bd[1] = word;
    if (w == g + 2) bd[2] = word;
    if (w == g + 3) bd[3] = word;
}

// 6) suppress v6 — SINGLE WAVE, register-resident remv, zero inter-wave sync.
//    lane l owns remv words l (r0) and l+64 (r1). Per keep: 3 rl64 from the
//    register band (words c..c+2) + 2 full-row mask loads into a 4-deep
//    statically-unrolled pend register file, consumed 3 chunks later (~900cy
//    slack). Band prefetched 4 chunks ahead (4 static sets). Waves 1-3 idle
//    until the output write.
__global__ void __launch_bounds__(256) suppress_kernel(
        const unsigned long long* __restrict__ mask,
        const unsigned long long* __restrict__ band,
        const float* __restrict__ sortedBox,
        float* __restrict__ out) {
    int bb = blockIdx.x;
    int tid = threadIdx.x;
    int lane = tid & 63, wv = tid >> 6;
    __shared__ int keptAll[POST_NMS];
    __shared__ int stotal;

    const unsigned long long* M  = mask + (size_t)bb * NW * ROWS;
    const unsigned long long* Bd = band + (size_t)bb * ROWS * 4;
    const float* sb = sortedBox + (size_t)bb * ROWS * 8;
    float* ob = out + (size_t)bb * POST_NMS * 7;

    if (wv == 0) {
        const unsigned long long* rowp0 = M + (size_t)lane * ROWS;
        int l1 = lane + 64; if (l1 > NW - 1) l1 = NW - 1;   // clamp (lanes>=30 junk, never read)
        const unsigned long long* rowp1 = M + (size_t)l1 * ROWS;

        unsigned long long r0 = 0, r1 = 0;
        if (lane == NW - 1 - 64)            // word 93 tail guard (lane 29)
            r1 = ~((1ull << (PRE_NMS - (NW - 1) * 64)) - 1ull);

        unsigned long long pend[4][8][2];
#pragma unroll
        for (int q = 0; q < 4; ++q)
#pragma unroll
            for (int i = 0; i < 8; ++i) { pend[q][i][0] = 0; pend[q][i][1] = 0; }

        unsigned long long bd0[3], bd1[3], bd2[3], bd3[3];
#define BAND_LOAD(CH, BD)                                                      \
        {   const ulonglong2* bp_ = reinterpret_cast<const ulonglong2*>(       \
                &Bd[(size_t)((CH) * 64 + lane) * 4]);                          \
            ulonglong2 va_ = bp_[0];                                           \
            BD[0] = va_.x; BD[1] = va_.y;                                      \
            BD[2] = Bd[(size_t)((CH) * 64 + lane) * 4 + 2]; }
        BAND_LOAD(0, bd0)
        BAND_LOAD(1, bd1)
        BAND_LOAD(2, bd2)
        BAND_LOAD(3, bd3)

        unsigned long long supCur = 0, S1 = 0, S2 = 0;
        int kt = 0;
        bool stop = false;

#define CHUNK_BODY(CVAL, P, BD)                                                \
        if (!stop) {                                                          \
            const int c = (CVAL);                                             \
            {   /* consume pend set (P+1)&3 (issued at chunk c-3) */          \
                unsigned long long a0 = 0, a1 = 0;                            \
                _Pragma("unroll")                                              \
                for (int i = 0; i < 8; ++i) {                                  \
                    a0 |= pend[((P) + 1) & 3][i][0];                           \
                    a1 |= pend[((P) + 1) & 3][i][1];                           \
                }                                                              \
                r0 |= a0; r1 |= a1;                                            \
                _Pragma("unroll")                                              \
                for (int i = 0; i < 8; ++i) {                                  \
                    pend[((P) + 1) & 3][i][0] = 0;                             \
                    pend[((P) + 1) & 3][i][1] = 0;                             \
                }                                                              \
            }                                                                  \
            unsigned long long cur = (c < 64) ? rl64(r0, c) : rl64(r1, c - 64);\
            unsigned long long alive = ~(cur | supCur);                        \
            int nk = 0;                                                        \
            _Pragma("unroll")                                                  \
            for (int i = 0; i < 8; ++i) {                                      \
                if (alive && kt + nk < POST_NMS) {                             \
                    int b_ = (int)__builtin_ctzll(alive);                      \
                    int bs = __builtin_amdgcn_readfirstlane(b_);               \
                    int R = c * 64 + bs;                                       \
                    if (lane == 0) keptAll[kt + nk] = R;                       \
                    unsigned long long dr = rl64(BD[0], bs);                   \
                    S1 |= rl64(BD[1], bs);                                     \
                    S2 |= rl64(BD[2], bs);                                     \
                    pend[(P)][i][0] = rowp0[R];                                \
                    pend[(P)][i][1] = rowp1[R];                                \
                    ++nk;                                                      \
                    alive &= ~(dr | (1ull << bs));                             \
                }                                                              \
            }                                                                  \
            kt += nk;                                                          \
            while (alive && kt < POST_NMS) {   /* overflow: batch of 4 */      \
                unsigned long long o00 = 0, o01 = 0, o10 = 0, o11 = 0,         \
                                   o20 = 0, o21 = 0, o30 = 0, o31 = 0;         \
                _Pragma("unroll")                                              \
                for (int i = 0; i < 4; ++i) {                                  \
                    if (alive && kt < POST_NMS) {                              \
                        int b_ = (int)__builtin_ctzll(alive);                  \
                        int bs = __builtin_amdgcn_readfirstlane(b_);           \
                        int R = c * 64 + bs;                                   \
                        if (lane == 0) keptAll[kt] = R;                        \
                        unsigned long long dr = rl64(BD[0], bs);               \
                        S1 |= rl64(BD[1], bs);                                 \
                        S2 |= rl64(BD[2], bs);                                 \
                        if (i == 0)      { o00 = rowp0[R]; o01 = rowp1[R]; }   \
                        else if (i == 1) { o10 = rowp0[R]; o11 = rowp1[R]; }   \
                        else if (i == 2) { o20 = rowp0[R]; o21 = rowp1[R]; }   \
                        else             { o30 = rowp0[R]; o31 = rowp1[R]; }   \
                        ++kt;                                                  \
                        alive &= ~(dr | (1ull << bs));                         \
                    }                                                          \
                }                                                              \
                r0 |= o00 | o10 | o20 | o30;                                   \
                r1 |= o01 | o11 | o21 | o31;                                   \
            }                                                                  \
            if (kt >= POST_NMS) stop = true;                                   \
            supCur = S1; S1 = S2; S2 = 0;                                      \
            if (c + 4 < NW) BAND_LOAD(c + 4, BD)                               \
        }

        for (int cb = 0; cb < 92; cb += 4) {
            CHUNK_BODY(cb + 0, 0, bd0)
            CHUNK_BODY(cb + 1, 1, bd1)
            CHUNK_BODY(cb + 2, 2, bd2)
            CHUNK_BODY(cb + 3, 3, bd3)
        }
        CHUNK_BODY(92, 0, bd0)
        CHUNK_BODY(93, 1, bd1)
#undef CHUNK_BODY
#undef BAND_LOAD
        if (lane == 0) stotal = kt;
    }
    __syncthreads();

    int total = stotal;
    for (int e = tid; e < total * 7; e += 256) {
        int i = e / 7, j = e - i * 7;
        ob[e] = sb[(size_t)keptAll[i] * 8 + (j == 0 ? 7 : j - 1)];
    }
    for (int idx = total * 7 + tid; idx < POST_NMS * 7; idx += 256)
        ob[idx] = 0.0f;
}

extern "C" void kernel_launch(void* const* d_in, const int* in_sizes, int n_in,
                              void* d_out, int out_size, void* d_ws, size_t ws_size,
                              hipStream_t stream) {
    const float* scores_map = (const float*)d_in[0];
    const float* bbox_frame = (const float*)d_in[1];
    const float* im_info    = (const float*)d_in[2];
    const float* anchors    = (const float*)d_in[3];
    float* out = (float*)d_out;

    // workspace layout (bytes) — total 10,088,976 (same footprint)
    char* ws = (char*)d_ws;
    unsigned long long* mask  = (unsigned long long*)(ws + 0);          // 9,048,064
    unsigned int* binbase     = (unsigned int*)(ws + 0);                // aliases mask
    unsigned int* histR       = (unsigned int*)(ws + 524288);           // aliases mask: 4,194,304
    float* sortedBox          = (float*)(ws + 9048064);                 // 385,024
    unsigned long long* cand  = (unsigned long long*)(ws + 9433088);    // 131,072
    unsigned int* hist        = (unsigned int*)(ws + 9564160);          // 524,288 canonical
    unsigned long long* band  = (unsigned long long*)(ws + 9564160);    // aliases hist
                                                                        // (hist dead after decode) 385,024
    unsigned int* thr         = (unsigned int*)(ws + 10088448);         // 16
    unsigned int* partials    = (unsigned int*)(ws + 10088464);         // 512

    hipMemsetAsync(histR, 0, (size_t)NREP * B_ * NBIN * 4, stream);

    int total = B_ * N_;
    hist_kernel<<<(total + 255) / 256, 256, 0, stream>>>(scores_map, histR);
    partial_kernel<<<dim3(64, B_), 256, 0, stream>>>(histR, partials);
    rewrite_kernel<<<dim3(64, B_), 256, 0, stream>>>(histR, hist, binbase, partials, thr);
    compact_kernel<<<total / 256, 256, 0, stream>>>(scores_map, thr, cand, hist);
    bucket_decode<<<B_ * CAP / 256, 256, 0, stream>>>(cand, hist, binbase, thr,
                                                      bbox_frame, im_info, anchors,
                                                      sortedBox);
    mask_build<<<dim3(NW * NW, B_), 64, 0, stream>>>(sortedBox, mask, band);
    suppress_kernel<<<B_, 256, 0, stream>>>(mask, band, sortedBox, out);
}